// Round 7
// baseline (853.642 us; speedup 1.0000x reference)
//
#include <hip/hip_runtime.h>
#include <hip/hip_bf16.h>

typedef short v8s __attribute__((ext_vector_type(8)));
typedef float v4f __attribute__((ext_vector_type(4)));
typedef unsigned short bf16u;

#define NB    32
#define NCDD  5
#define NHIS  50
#define NL    32
#define NE    300
#define NEP   320
#define NH    16
#define NQD   200
#define NR    256
#define NMASK 40
#define NITEM 1760
#define SCALE 0.05773502691896258f  /* 1/sqrt(300) */

// workspace offsets (bytes), all 256-aligned
#define WQB_OFF  0u          /* wqB [16][320][320] bf16 = 3,276,800 ([h][e][f]) */
#define WVT_OFF  3276800u    /* wvT [16][16][320]  bf16 =   163,840 */
#define WKT_OFF  3440640u    /* wkT [256][256]     bf16 =   131,072 */
#define REP_OFF  3571712u    /* rep [1760][256]    f32  = 1,802,240 */
#define HVAL_OFF 5373952u    /* hval [1760][32][256] bf16 = 28,835,840 */

#define XS  328  /* x LDS row stride: 656B -> 2-way bank step (free) */
#define TSX 72   /* xv row stride: 144B, 16B-aligned, ~2-way */
#define VS  264  /* val row stride: 528B, 16B-aligned */

__device__ __forceinline__ float b2f(bf16u u) {
  return __uint_as_float(((unsigned int)u) << 16);
}
// native RNE convert (bit-identical to the old manual round-to-nearest-even;
// compiler fuses adjacent casts into v_cvt_pk_bf16_f32 -- m240)
__device__ __forceinline__ bf16u f2b(float f) {
  __hip_bfloat16 h = __float2bfloat16(f);
  return *reinterpret_cast<bf16u*>(&h);
}

#define MFMA(a, b, c) __builtin_amdgcn_mfma_f32_16x16x32_bf16((a), (b), (c), 0, 0, 0)
#define Z4 ((v4f){0.f, 0.f, 0.f, 0.f})
#define PACKU2(p, t)                                                      \
  do {                                                                    \
    (p).x = (unsigned)f2b((t)[0]) | ((unsigned)f2b((t)[1]) << 16);        \
    (p).y = (unsigned)f2b((t)[2]) | ((unsigned)f2b((t)[3]) << 16);        \
  } while (0)

// ---------------------------------------------------------------------------
// prep: f32 weights -> bf16, zero-padded.
// ---------------------------------------------------------------------------
__global__ void prep_kernel(const float* __restrict__ wq,
                            const float* __restrict__ wvp,
                            const float* __restrict__ wk,
                            bf16u* __restrict__ wqB,
                            bf16u* __restrict__ wvT,
                            bf16u* __restrict__ wkT) {
  int idx = blockIdx.x * 256 + threadIdx.x;
  const int N1 = 16 * 320 * 320;
  const int N2 = 16 * 16 * 320;
  const int N3 = 256 * 256;
  if (idx < N1) {
    int h = idx / (320 * 320);
    int r = idx % (320 * 320);
    int e = r / 320, f = r % 320;
    wqB[idx] = (e < NE && f < NE) ? f2b(wq[h * 90000 + e * 300 + f]) : (bf16u)0;
  } else if (idx < N1 + N2) {
    int i = idx - N1;
    int h = i / (16 * 320);
    int r = i % (16 * 320);
    int v = r / 320, e = r % 320;
    wvT[i] = (e < NE) ? f2b(wvp[h * 4800 + e * 16 + v]) : (bf16u)0;
  } else if (idx < N1 + N2 + N3) {
    int i = idx - N1 - N2;
    int d = i / 256, rr = i % 256;
    wkT[i] = (d < NQD) ? f2b(wk[rr * 200 + d]) : (bf16u)0;
  }
}

// ---------------------------------------------------------------------------
// encode: grid = 880 2-item blocks; 512 thr (8 waves); 160.5 KB LDS, 1 blk/CU.
// ROUND-7: R4 (553us) structure kept verbatim (3 pipelining attempts all
// regressed); this round cuts the two biggest measured non-MFMA pipes:
//  * DS pipe (~200us/CU est.): 64-e chunks (5/head, was 10 of 32-e). Per ks
//    the same 4 x_s B-reads feed 16 MFMAs (was 8) -> t-loop LDS reads halve.
//    Wave scratch becomes [64 tok][64 e], stride 128B, XOR-swizzled
//    (byte ^= (row&7)<<4) on BOTH writes and reads (guide G4); all five
//    scratch access patterns verified 8-lanes-per-bank-quad = optimal.
//  * VALU pipe (~75us): manual 5-op f2b -> native __float2bfloat16 (RNE,
//    bit-identical; compiler fuses into v_cvt_pk_bf16_f32).
// Tails (softmax/xv/v), keyw/rep/hval, select: R4-verbatim (only scratch
// addressing goes through scr_at).
// ---------------------------------------------------------------------------
__device__ __forceinline__ bf16u* scr_at(bf16u* base, int row, int bytecol) {
  return (bf16u*)((char*)base + row * 128 + (bytecol ^ ((row & 7) << 4)));
}
__device__ __forceinline__ const bf16u* scr_atc(const bf16u* base, int row,
                                                int bytecol) {
  return (const bf16u*)((const char*)base + row * 128 +
                        (bytecol ^ ((row & 7) << 4)));
}

__global__ __launch_bounds__(512, 2) void encode_kernel(
    const int* __restrict__ cand_tok, const int* __restrict__ clk_tok,
    const float* __restrict__ emb,
    const bf16u* __restrict__ wqB, const bf16u* __restrict__ wvT,
    const bf16u* __restrict__ wkT,
    const float* __restrict__ bk, const float* __restrict__ qw,
    float* __restrict__ rep, bf16u* __restrict__ hval) {
  __shared__ alignas(16) bf16u x_s[64 * XS];        // 41,984 B
  __shared__ alignas(16) bf16u scr_s[8][64 * 64];   // 65,536 B (per-wave 8KB)
  __shared__ alignas(16) bf16u xv_s[8][16 * TSX];   // 18,432 B (per-wave)
  __shared__ alignas(16) bf16u val_s[2 * 32 * VS];  // 33,792 B
  __shared__ float wl_s[2][64];                     //    512 B
  __shared__ float ww_s[64];                        //    256 B
  // total 160,512 B <= 163,840 -> 1 block/CU

  const int tid = threadIdx.x;
  const int lane = tid & 63;
  const int w = tid >> 6;     // wave 0..7
  const int q4 = lane >> 4;
  const int l15 = lane & 15;
  const int g0 = blockIdx.x * 2;

  // gather 2 items of x straight from emb (f32 -> bf16), pad cols 300..327
  for (int c = tid; c < 2 * 32 * 82; c += 512) {
    int item = c / (32 * 82);
    int rr = c % (32 * 82);
    int l = rr / 82, j = rr % 82;
    bf16u tmp[4] = {0, 0, 0, 0};
    if (j < 75) {
      int gi = g0 + item;
      int tok = (gi < NB * NCDD) ? cand_tok[gi * NL + l]
                                 : clk_tok[(gi - NB * NCDD) * NL + l];
      float4 d = *(const float4*)(emb + (size_t)tok * NE + j * 4);
      tmp[0] = f2b(d.x); tmp[1] = f2b(d.y); tmp[2] = f2b(d.z); tmp[3] = f2b(d.w);
    }
    *(uint2*)(&x_s[item * 32 * XS + l * XS + j * 4]) = *(const uint2*)tmp;
  }
  __syncthreads();

  bf16u* tb = &scr_s[w][0];   // wave scratch [64 tok rows][64 e], swizzled
  bf16u* xvb = &xv_s[w][0];   // wave xv [16 v][TSX]

  for (int hh = 0; hh < 2; ++hh) {
    const int h = (w << 1) | hh;
    const bf16u* wqh = wqB + (size_t)h * 102400;

    // s accumulators: [item][l-tile][m-tile], 8 independent MFMA chains
    v4f s[2][2][2];
#pragma unroll
    for (int i = 0; i < 2; ++i)
#pragma unroll
      for (int lt = 0; lt < 2; ++lt)
#pragma unroll
        for (int mt = 0; mt < 2; ++mt) s[i][lt][mt] = Z4;

#pragma unroll 1
    for (int ch = 0; ch < 5; ++ch) {
      // ---- t-chunk: t[e=ch*64..+63][tok 0..63] = Wq @ x^T (contract f) ----
      v4f t[4][4];  // [e-tile j][tok-tile tt]
#pragma unroll
      for (int j = 0; j < 4; ++j)
#pragma unroll
        for (int tt = 0; tt < 4; ++tt) t[j][tt] = Z4;
      const bf16u* ap = wqh + (size_t)(ch * 64 + l15) * NEP + q4 * 8;
#pragma unroll
      for (int ks = 0; ks < 10; ++ks) {
        v8s a0 = *(const v8s*)(ap + ks * 32);             // e rows +0..15
        v8s a1 = *(const v8s*)(ap + 16 * NEP + ks * 32);  // e rows +16..31
        v8s a2 = *(const v8s*)(ap + 32 * NEP + ks * 32);  // e rows +32..47
        v8s a3 = *(const v8s*)(ap + 48 * NEP + ks * 32);  // e rows +48..63
        v8s b0 = *(const v8s*)(&x_s[l15 * XS + ks * 32 + q4 * 8]);
        v8s b1 = *(const v8s*)(&x_s[(16 + l15) * XS + ks * 32 + q4 * 8]);
        v8s b2 = *(const v8s*)(&x_s[(32 + l15) * XS + ks * 32 + q4 * 8]);
        v8s b3 = *(const v8s*)(&x_s[(48 + l15) * XS + ks * 32 + q4 * 8]);
        t[0][0] = MFMA(a0, b0, t[0][0]); t[0][1] = MFMA(a0, b1, t[0][1]);
        t[0][2] = MFMA(a0, b2, t[0][2]); t[0][3] = MFMA(a0, b3, t[0][3]);
        t[1][0] = MFMA(a1, b0, t[1][0]); t[1][1] = MFMA(a1, b1, t[1][1]);
        t[1][2] = MFMA(a1, b2, t[1][2]); t[1][3] = MFMA(a1, b3, t[1][3]);
        t[2][0] = MFMA(a2, b0, t[2][0]); t[2][1] = MFMA(a2, b1, t[2][1]);
        t[2][2] = MFMA(a2, b2, t[2][2]); t[2][3] = MFMA(a2, b3, t[2][3]);
        t[3][0] = MFMA(a3, b0, t[3][0]); t[3][1] = MFMA(a3, b1, t[3][1]);
        t[3][2] = MFMA(a3, b2, t[3][2]); t[3][3] = MFMA(a3, b3, t[3][3]);
      }
      // pack: acc col=l15=tok-in-tile, rows=4 consecutive e -> scratch
      // [tok-row][e-local], swizzled 8B writes
#pragma unroll
      for (int j = 0; j < 4; ++j)
#pragma unroll
        for (int tt = 0; tt < 4; ++tt) {
          uint2 p;
          PACKU2(p, t[j][tt]);
          *(uint2*)scr_at(tb, tt * 16 + l15, j * 32 + q4 * 8) = p;
        }
      // ---- s(ch): s[l][m] += tT[l][e-chunk] * x[m][e-chunk], 2 k-subs ----
#pragma unroll
      for (int i = 0; i < 2; ++i)
#pragma unroll
        for (int sub = 0; sub < 2; ++sub) {
          v8s ta0 = *(const v8s*)scr_atc(tb, (i * 2 + 0) * 16 + l15,
                                         sub * 64 + q4 * 16);
          v8s ta1 = *(const v8s*)scr_atc(tb, (i * 2 + 1) * 16 + l15,
                                         sub * 64 + q4 * 16);
          v8s xb0 = *(const v8s*)(
              &x_s[(i * 32 + l15) * XS + ch * 64 + sub * 32 + q4 * 8]);
          v8s xb1 = *(const v8s*)(
              &x_s[(i * 32 + 16 + l15) * XS + ch * 64 + sub * 32 + q4 * 8]);
          s[i][0][0] = MFMA(ta0, xb0, s[i][0][0]);
          s[i][0][1] = MFMA(ta0, xb1, s[i][0][1]);
          s[i][1][0] = MFMA(ta1, xb0, s[i][1][0]);
          s[i][1][1] = MFMA(ta1, xb1, s[i][1][1]);
        }
    }

    // ---- s -> scratch (bf16 [l-row][m-col], swizzled scalar stores) ----
#pragma unroll
    for (int i = 0; i < 2; ++i)
#pragma unroll
      for (int lt = 0; lt < 2; ++lt)
#pragma unroll
        for (int mt = 0; mt < 2; ++mt)
#pragma unroll
          for (int r = 0; r < 4; ++r)
            *scr_at(tb, i * 32 + lt * 16 + q4 * 4 + r, (mt * 16 + l15) * 2) =
                f2b(s[i][lt][mt][r]);

    // ---- softmax over m, in-place (R4-verbatim, 4 passes) ----
#pragma unroll
    for (int p = 0; p < 4; ++p) {
      int row = (p >> 1) * 32 + (p & 1) * 16 + (lane >> 2);
      int jj = lane & 3;
      v8s sv = *(const v8s*)scr_atc(tb, row, jj * 16);
      float v[8];
      float mx = -1e30f;
#pragma unroll
      for (int k = 0; k < 8; ++k) {
        v[k] = b2f((bf16u)sv[k]) * SCALE;
        mx = fmaxf(mx, v[k]);
      }
      mx = fmaxf(mx, __shfl_xor(mx, 1));
      mx = fmaxf(mx, __shfl_xor(mx, 2));
      float sum = 0.f;
#pragma unroll
      for (int k = 0; k < 8; ++k) { v[k] = __expf(v[k] - mx); sum += v[k]; }
      sum += __shfl_xor(sum, 1);
      sum += __shfl_xor(sum, 2);
      float inv = 1.f / sum;
      bf16u tmp[8];
#pragma unroll
      for (int k = 0; k < 8; ++k) tmp[k] = f2b(v[k] * inv);
      *(uint4*)scr_at(tb, row, jj * 16) = *(const uint4*)tmp;
    }

    // ---- xv = x @ WvT[h] (both items; B shared) -> xv_s [v][tok64] ----
    {
      v4f xa[2][2];  // [item][m-tile]
#pragma unroll
      for (int i = 0; i < 2; ++i)
#pragma unroll
        for (int mt = 0; mt < 2; ++mt) xa[i][mt] = Z4;
      const bf16u* vb = wvT + (size_t)h * (16 * NEP) + l15 * NEP + q4 * 8;
#pragma unroll
      for (int ks = 0; ks < 10; ++ks) {
        v8s b = *(const v8s*)(vb + ks * 32);
#pragma unroll
        for (int i = 0; i < 2; ++i)
#pragma unroll
          for (int mt = 0; mt < 2; ++mt) {
            v8s a = *(const v8s*)(
                &x_s[(i * 32 + mt * 16 + l15) * XS + ks * 32 + q4 * 8]);
            xa[i][mt] = MFMA(a, b, xa[i][mt]);
          }
      }
      // acc col=l15=v, rows=4 toks -> [v-row l15][tok-col]
#pragma unroll
      for (int i = 0; i < 2; ++i)
#pragma unroll
        for (int mt = 0; mt < 2; ++mt) {
          uint2 p;
          PACKU2(p, xa[i][mt]);
          *(uint2*)(xvb + l15 * TSX + i * 32 + mt * 16 + q4 * 4) = p;
        }
    }

    // ---- v = a @ xv -> val_s[:, h*16 + 0..15] (wave-private columns) ----
#pragma unroll
    for (int i = 0; i < 2; ++i)
#pragma unroll
      for (int lt = 0; lt < 2; ++lt) {
        v8s af = *(const v8s*)scr_atc(tb, (i * 2 + lt) * 16 + l15, q4 * 16);
        v8s bv = *(const v8s*)(xvb + l15 * TSX + i * 32 + q4 * 8);
        v4f vv = MFMA(af, bv, Z4);
#pragma unroll
        for (int r = 0; r < 4; ++r)
          val_s[i * (32 * VS) + (lt * 16 + q4 * 4 + r) * VS + h * 16 + l15] =
              f2b(vv[r]);
      }
  }
  __syncthreads();

  // ---- keyw = tanh(val@WkT + bk); wl = SCALE * qw . keyw (R4 verbatim) ----
  {
    int itm = w >> 2, lt = (w >> 1) & 1, half = w & 1;
    const bf16u* vrow = &val_s[itm * (32 * VS) + (lt * 16 + l15) * VS + q4 * 8];
    v8s af2[8];
#pragma unroll
    for (int ks = 0; ks < 8; ++ks) af2[ks] = *(const v8s*)(vrow + ks * 32);
    float wlp[4] = {0.f, 0.f, 0.f, 0.f};
#pragma unroll
    for (int k = 0; k < 8; ++k) {
      int d = (half * 8 + k) * 16 + l15;
      float bkf = (d < NQD) ? bk[d] : 0.f;
      float qwf = (d < NQD) ? qw[d] : 0.f;
      v4f acc = Z4;
      const bf16u* bp2 = wkT + d * NR + q4 * 8;
#pragma unroll
      for (int ks = 0; ks < 8; ++ks) {
        v8s b = *(const v8s*)(bp2 + ks * 32);
        acc = MFMA(af2[ks], b, acc);
      }
#pragma unroll
      for (int r = 0; r < 4; ++r)
        wlp[r] += tanhf(acc[r] + bkf) * qwf;
    }
#pragma unroll
    for (int r = 0; r < 4; ++r) {
      float tv = wlp[r] * SCALE;
      tv += __shfl_xor(tv, 1);
      tv += __shfl_xor(tv, 2);
      tv += __shfl_xor(tv, 4);
      tv += __shfl_xor(tv, 8);
      if (l15 == 0) wl_s[half][itm * 32 + lt * 16 + q4 * 4 + r] = tv;
    }
  }
  __syncthreads();

  // ---- ww = softmax(wl) per item (lanes 0-31 item0, 32-63 item1) ----
  if (tid < 64) {
    float v = wl_s[0][tid] + wl_s[1][tid];
    float mx = v;
#pragma unroll
    for (int off = 1; off < 32; off <<= 1) mx = fmaxf(mx, __shfl_xor(mx, off, 32));
    float e = __expf(v - mx);
    float sum = e;
#pragma unroll
    for (int off = 1; off < 32; off <<= 1) sum += __shfl_xor(sum, off, 32);
    ww_s[tid] = e / sum;
  }
  __syncthreads();

  // ---- rep[r] = sum_l ww[l]*val[l][r] ----
  {
    int itm = tid >> 8, r = tid & 255;
    const bf16u* vb2 = &val_s[itm * (32 * VS) + r];
    float sv = 0.f;
#pragma unroll 8
    for (int l = 0; l < 32; ++l) sv += ww_s[itm * 32 + l] * b2f(vb2[l * VS]);
    rep[(size_t)(g0 + itm) * NR + r] = sv;
  }
  // ---- hval writeback (clicked items only), coalesced uint4 ----
  if (g0 >= NB * NCDD) {
    for (int c = tid; c < 2048; c += 512) {
      int itm = c >> 10, l = (c >> 5) & 31, j = c & 31;
      *(uint4*)(hval + (size_t)(g0 + itm) * (NL * NR) + l * NR + j * 8) =
          *(const uint4*)(&val_s[itm * (32 * VS) + l * VS + j * 8]);
    }
  }
}

// ---------------------------------------------------------------------------
// select: one block per (b,c): score[h] = cdd_rep.his_rep + gumbel (h<40),
// argmax, gather. grid = 160.
// ---------------------------------------------------------------------------
__global__ __launch_bounds__(256) void select_kernel(
    const float* __restrict__ rep, const float* __restrict__ gumbel,
    const bf16u* __restrict__ hval, float* __restrict__ out) {
  __shared__ float score[NMASK];
  __shared__ int hstar;
  const float* cdd_rep = rep;
  const float* his_rep = rep + (size_t)(NB * NCDD) * NR;
  const bf16u* his_val = hval + (size_t)(NB * NCDD) * (NL * NR);
  int b = blockIdx.x / NCDD, c = blockIdx.x % NCDD;
  int tid = threadIdx.x, lane = tid & 63, wv = tid >> 6;
  const float* cr = cdd_rep + (size_t)(b * NCDD + c) * NR;
  for (int h = wv; h < NMASK; h += 4) {
    const float* hr = his_rep + (size_t)(b * NHIS + h) * NR;
    float s = 0.f;
#pragma unroll
    for (int j = 0; j < 4; ++j) s += cr[lane * 4 + j] * hr[lane * 4 + j];
#pragma unroll
    for (int off = 1; off < 64; off <<= 1) s += __shfl_xor(s, off);
    if (lane == 0)
      score[h] = s + gumbel[(b * NCDD + c) * NHIS + h];
  }
  __syncthreads();
  if (tid == 0) {
    float best = -1e30f;
    int bi = 0;
    for (int h = 0; h < NMASK; ++h) {
      float v = score[h];
      if (v > best) { best = v; bi = h; }  // strict > keeps first max
    }
    hstar = bi;
  }
  __syncthreads();
  const bf16u* src = his_val + (size_t)(b * NHIS + hstar) * (NL * NR);
  float* dst = out + (size_t)(b * NCDD + c) * (NL * NR);
  for (int k = tid; k < 2048; k += 256) {
    const bf16u* sp = src + k * 4;
    float4 o;
    o.x = b2f(sp[0]); o.y = b2f(sp[1]); o.z = b2f(sp[2]); o.w = b2f(sp[3]);
    *(float4*)(dst + k * 4) = o;
  }
}

extern "C" void kernel_launch(void* const* d_in, const int* in_sizes, int n_in,
                              void* d_out, int out_size, void* d_ws, size_t ws_size,
                              hipStream_t stream) {
  (void)in_sizes; (void)n_in; (void)out_size; (void)ws_size;
  const int* cand = (const int*)d_in[0];
  const int* clk = (const int*)d_in[1];
  // d_in[2] his_mask (static: h>=40), d_in[3]/d_in[4] pads: unused
  const float* gum = (const float*)d_in[5];
  const float* emb = (const float*)d_in[6];
  const float* wq = (const float*)d_in[7];
  const float* wvp = (const float*)d_in[8];
  const float* wk = (const float*)d_in[9];
  const float* bk = (const float*)d_in[10];
  const float* qw = (const float*)d_in[11];

  char* ws = (char*)d_ws;
  bf16u* wqB = (bf16u*)(ws + WQB_OFF);
  bf16u* wvT = (bf16u*)(ws + WVT_OFF);
  bf16u* wkT = (bf16u*)(ws + WKT_OFF);
  float* rep = (float*)(ws + REP_OFF);
  bf16u* hval = (bf16u*)(ws + HVAL_OFF);

  const int totalT = 16 * 320 * 320 + 16 * 16 * 320 + 256 * 256;  // 1,785,856
  hipLaunchKernelGGL(prep_kernel, dim3((totalT + 255) / 256), dim3(256), 0, stream,
                     wq, wvp, wk, wqB, wvT, wkT);
  hipLaunchKernelGGL(encode_kernel, dim3(NITEM / 2), dim3(512), 0, stream,
                     cand, clk, emb, wqB, wvT, wkT, bk, qw, rep, hval);
  hipLaunchKernelGGL(select_kernel, dim3(NB * NCDD), dim3(256), 0, stream,
                     rep, gum, hval, (float*)d_out);
}

// Round 8
// 839.108 us; speedup vs baseline: 1.0173x; 1.0173x over previous
//
#include <hip/hip_runtime.h>
#include <hip/hip_bf16.h>

typedef short v8s __attribute__((ext_vector_type(8)));
typedef float v4f __attribute__((ext_vector_type(4)));
typedef unsigned short bf16u;

#define NB    32
#define NCDD  5
#define NHIS  50
#define NL    32
#define NE    300
#define NEP   320
#define NH    16
#define NQD   200
#define NR    256
#define NMASK 40
#define NITEM 1760
#define SCALE 0.05773502691896258f  /* 1/sqrt(300) */

// workspace offsets (bytes), all 256-aligned
#define WQB_OFF  0u          /* wqB [16][320][320] bf16 = 3,276,800 ([h][e][f]) */
#define WVT_OFF  3276800u    /* wvT [16][16][320]  bf16 =   163,840 */
#define WKT_OFF  3440640u    /* wkT [256][256]     bf16 =   131,072 */
#define REP_OFF  3571712u    /* rep [1760][256]    f32  = 1,802,240 */
#define HVAL_OFF 5373952u    /* hval [1760][32][256] bf16 = 28,835,840 */

#define XS  328  /* x LDS row stride: 656B -> 2-way bank step (free) */
#define TS  40   /* wave scratch row stride: 80B -> 2-way (free), 16B-aligned */
#define TSX 72   /* xv row stride: 144B, 16B-aligned, ~2-way */
#define VS  264  /* val row stride: 528B, 16B-aligned */

__device__ __forceinline__ float b2f(bf16u u) {
  return __uint_as_float(((unsigned int)u) << 16);
}
// native RNE convert -- bit-identical to manual RNE (proven: R7 absmax equal);
// compiler fuses adjacent casts into v_cvt_pk_bf16_f32.
__device__ __forceinline__ bf16u f2b(float f) {
  __hip_bfloat16 h = __float2bfloat16(f);
  return *reinterpret_cast<bf16u*>(&h);
}

#define MFMA(a, b, c) __builtin_amdgcn_mfma_f32_16x16x32_bf16((a), (b), (c), 0, 0, 0)
#define Z4 ((v4f){0.f, 0.f, 0.f, 0.f})
#define PACKU2(p, t)                                                      \
  do {                                                                    \
    (p).x = (unsigned)f2b((t)[0]) | ((unsigned)f2b((t)[1]) << 16);        \
    (p).y = (unsigned)f2b((t)[2]) | ((unsigned)f2b((t)[3]) << 16);        \
  } while (0)

// ---------------------------------------------------------------------------
// prep: f32 weights -> bf16, zero-padded.
// ---------------------------------------------------------------------------
__global__ void prep_kernel(const float* __restrict__ wq,
                            const float* __restrict__ wvp,
                            const float* __restrict__ wk,
                            bf16u* __restrict__ wqB,
                            bf16u* __restrict__ wvT,
                            bf16u* __restrict__ wkT) {
  int idx = blockIdx.x * 256 + threadIdx.x;
  const int N1 = 16 * 320 * 320;
  const int N2 = 16 * 16 * 320;
  const int N3 = 256 * 256;
  if (idx < N1) {
    int h = idx / (320 * 320);
    int r = idx % (320 * 320);
    int e = r / 320, f = r % 320;
    wqB[idx] = (e < NE && f < NE) ? f2b(wq[h * 90000 + e * 300 + f]) : (bf16u)0;
  } else if (idx < N1 + N2) {
    int i = idx - N1;
    int h = i / (16 * 320);
    int r = i % (16 * 320);
    int v = r / 320, e = r % 320;
    wvT[i] = (e < NE) ? f2b(wvp[h * 4800 + e * 16 + v]) : (bf16u)0;
  } else if (idx < N1 + N2 + N3) {
    int i = idx - N1 - N2;
    int d = i / 256, rr = i % 256;
    wkT[i] = (d < NQD) ? f2b(wk[rr * 200 + d]) : (bf16u)0;
  }
}

// ---------------------------------------------------------------------------
// encode: grid = 880 2-item blocks; 256 thr (4 waves); 106 KB LDS, 1 blk/CU.
// ROUND-8: trade TLP for registers, spend registers on the DS pipe.
// Measured R4 breakdown: LDS pipe ~165us busy/CU (9600 DS instrs/block,
// 6400 of them t-loop x-reads) > MFMA 91us > VALU 75us. Every 512-thread
// schedule needing >256 regs/wave spilled (R1/R3/R5/R7) because 8 waves
// must co-reside (2/SIMD, file ~512/SIMD). 256-thread blocks -> 4 waves,
// 1/SIMD -> ~512 regs/wave budget:
//  * xr[4][10] v8s (160 VGPR) holds ALL of x in MFMA-fragment form, loaded
//    once; serves t-GEMM B, s-GEMM B (xr[tt][ch], index-identical to R4's
//    x_s read), and xv A. Deletes ~6400 DS reads + their bank conflicts.
//  * ch loop fully unrolled so xr indexing is compile-time (rule #20).
//  * 4 heads/wave, barrier-free head loop; layouts R4-verbatim.
// 1 wave/SIMD = pure-ILP regime: straight-line 80-MFMA chunks + deep
// compiler prefetch (200 spare regs) cover L2/LDS latency.
// ---------------------------------------------------------------------------
__global__ __launch_bounds__(256, 1) void encode_kernel(
    const int* __restrict__ cand_tok, const int* __restrict__ clk_tok,
    const float* __restrict__ emb,
    const bf16u* __restrict__ wqB, const bf16u* __restrict__ wvT,
    const bf16u* __restrict__ wkT,
    const float* __restrict__ bk, const float* __restrict__ qw,
    float* __restrict__ rep, bf16u* __restrict__ hval) {
  __shared__ alignas(16) bf16u x_s[64 * XS];        // 41,984 B
  __shared__ alignas(16) bf16u scr_s[4][64 * TS];   // 20,480 B (per-wave)
  __shared__ alignas(16) bf16u xv_s[4][16 * TSX];   //  9,216 B (per-wave)
  __shared__ alignas(16) bf16u val_s[2 * 32 * VS];  // 33,792 B
  __shared__ float wl_s[64];                        //    256 B
  __shared__ float ww_s[64];                        //    256 B
  // total 105,984 B -> 1 block/CU

  const int tid = threadIdx.x;
  const int lane = tid & 63;
  const int w = tid >> 6;     // wave 0..3
  const int q4 = lane >> 4;
  const int l15 = lane & 15;
  const int g0 = blockIdx.x * 2;

  // gather 2 items of x straight from emb (f32 -> bf16), pad cols 300..327
  for (int c = tid; c < 2 * 32 * 82; c += 256) {
    int item = c / (32 * 82);
    int rr = c % (32 * 82);
    int l = rr / 82, j = rr % 82;
    bf16u tmp[4] = {0, 0, 0, 0};
    if (j < 75) {
      int gi = g0 + item;
      int tok = (gi < NB * NCDD) ? cand_tok[gi * NL + l]
                                 : clk_tok[(gi - NB * NCDD) * NL + l];
      float4 d = *(const float4*)(emb + (size_t)tok * NE + j * 4);
      tmp[0] = f2b(d.x); tmp[1] = f2b(d.y); tmp[2] = f2b(d.z); tmp[3] = f2b(d.w);
    }
    *(uint2*)(&x_s[item * 32 * XS + l * XS + j * 4]) = *(const uint2*)tmp;
  }
  __syncthreads();

  // ---- load ALL x fragments to registers (one-time; 40 b128 per wave) ----
  // xr[tt][ks] = x[(tt*16+l15)][ks*32 + q4*8 .. +7]; serves t-B, s-B, xv-A.
  v8s xr[4][10];
#pragma unroll
  for (int tt = 0; tt < 4; ++tt)
#pragma unroll
    for (int ks = 0; ks < 10; ++ks)
      xr[tt][ks] = *(const v8s*)(&x_s[(tt * 16 + l15) * XS + ks * 32 + q4 * 8]);

  bf16u* tb = &scr_s[w][0];   // wave scratch [64 rows][TS]
  bf16u* xvb = &xv_s[w][0];   // wave xv [16 v][TSX]

#pragma unroll 1
  for (int hh = 0; hh < 4; ++hh) {
    const int h = (w << 2) | hh;
    const bf16u* wqh = wqB + (size_t)h * 102400;

    // s accumulators: [item][l-tile][m-tile], 8 independent MFMA chains
    v4f s[2][2][2];
#pragma unroll
    for (int i = 0; i < 2; ++i)
#pragma unroll
      for (int lt = 0; lt < 2; ++lt)
#pragma unroll
        for (int mt = 0; mt < 2; ++mt) s[i][lt][mt] = Z4;

#pragma unroll
    for (int ch = 0; ch < 10; ++ch) {
      // ---- t-chunk: t[e=ch*32..+31][tok 0..63] = Wq @ x^T (contract f) ----
      v4f t[2][4];  // [e-tile j][tok-tile tt]
#pragma unroll
      for (int j = 0; j < 2; ++j)
#pragma unroll
        for (int tt = 0; tt < 4; ++tt) t[j][tt] = Z4;
      const bf16u* ap = wqh + (size_t)(ch * 32 + l15) * NEP + q4 * 8;
#pragma unroll
      for (int ks = 0; ks < 10; ++ks) {
        v8s a0 = *(const v8s*)(ap + ks * 32);             // e rows ch*32+0..15
        v8s a1 = *(const v8s*)(ap + 16 * NEP + ks * 32);  // e rows +16..31
        t[0][0] = MFMA(a0, xr[0][ks], t[0][0]);
        t[0][1] = MFMA(a0, xr[1][ks], t[0][1]);
        t[0][2] = MFMA(a0, xr[2][ks], t[0][2]);
        t[0][3] = MFMA(a0, xr[3][ks], t[0][3]);
        t[1][0] = MFMA(a1, xr[0][ks], t[1][0]);
        t[1][1] = MFMA(a1, xr[1][ks], t[1][1]);
        t[1][2] = MFMA(a1, xr[2][ks], t[1][2]);
        t[1][3] = MFMA(a1, xr[3][ks], t[1][3]);
      }
      // pack: acc col=l15=tok-in-tile, rows=4 consecutive e -> scratch
      // [tok-row][e-local], 8B-aligned writes (R4-verbatim)
#pragma unroll
      for (int j = 0; j < 2; ++j)
#pragma unroll
        for (int tt = 0; tt < 4; ++tt) {
          uint2 p;
          PACKU2(p, t[j][tt]);
          *(uint2*)(tb + (tt * 16 + l15) * TS + j * 16 + q4 * 4) = p;
        }
      // ---- s(ch): s[l][m] += tT[l][e-chunk] * x[m][e-chunk] ----
      // B-frag = xr[i*2+mt][ch] (index-identical to R4's x_s read; ch static)
#pragma unroll
      for (int i = 0; i < 2; ++i)
#pragma unroll
        for (int lt = 0; lt < 2; ++lt) {
          v8s ta = *(const v8s*)(tb + ((i * 2 + lt) * 16 + l15) * TS + q4 * 8);
#pragma unroll
          for (int mt = 0; mt < 2; ++mt)
            s[i][lt][mt] = MFMA(ta, xr[i * 2 + mt][ch], s[i][lt][mt]);
        }
    }

    // ---- s -> scratch (bf16 [l-row][m-col], cols 0..31; R4-verbatim) ----
#pragma unroll
    for (int i = 0; i < 2; ++i)
#pragma unroll
      for (int lt = 0; lt < 2; ++lt)
#pragma unroll
        for (int mt = 0; mt < 2; ++mt)
#pragma unroll
          for (int r = 0; r < 4; ++r)
            tb[(i * 32 + lt * 16 + q4 * 4 + r) * TS + mt * 16 + l15] =
                f2b(s[i][lt][mt][r]);

    // ---- softmax over m, in-place (R4-verbatim, 4 passes) ----
#pragma unroll
    for (int p = 0; p < 4; ++p) {
      int row = (p >> 1) * 32 + (p & 1) * 16 + (lane >> 2);
      int jj = lane & 3;
      v8s sv = *(const v8s*)(tb + row * TS + jj * 8);
      float v[8];
      float mx = -1e30f;
#pragma unroll
      for (int k = 0; k < 8; ++k) {
        v[k] = b2f((bf16u)sv[k]) * SCALE;
        mx = fmaxf(mx, v[k]);
      }
      mx = fmaxf(mx, __shfl_xor(mx, 1));
      mx = fmaxf(mx, __shfl_xor(mx, 2));
      float sum = 0.f;
#pragma unroll
      for (int k = 0; k < 8; ++k) { v[k] = __expf(v[k] - mx); sum += v[k]; }
      sum += __shfl_xor(sum, 1);
      sum += __shfl_xor(sum, 2);
      float inv = 1.f / sum;
      bf16u tmp[8];
#pragma unroll
      for (int k = 0; k < 8; ++k) tmp[k] = f2b(v[k] * inv);
      *(uint4*)(tb + row * TS + jj * 8) = *(const uint4*)tmp;
    }

    // ---- xv = x @ WvT[h] (A from xr; both items) -> xv_s [v][tok64] ----
    {
      v4f xa[2][2];  // [item][m-tile]
#pragma unroll
      for (int i = 0; i < 2; ++i)
#pragma unroll
        for (int mt = 0; mt < 2; ++mt) xa[i][mt] = Z4;
      const bf16u* vb = wvT + (size_t)h * (16 * NEP) + l15 * NEP + q4 * 8;
#pragma unroll
      for (int ks = 0; ks < 10; ++ks) {
        v8s b = *(const v8s*)(vb + ks * 32);
#pragma unroll
        for (int i = 0; i < 2; ++i)
#pragma unroll
          for (int mt = 0; mt < 2; ++mt)
            xa[i][mt] = MFMA(xr[i * 2 + mt][ks], b, xa[i][mt]);
      }
      // acc col=l15=v, rows=4 toks -> [v-row l15][tok-col]
#pragma unroll
      for (int i = 0; i < 2; ++i)
#pragma unroll
        for (int mt = 0; mt < 2; ++mt) {
          uint2 p;
          PACKU2(p, xa[i][mt]);
          *(uint2*)(xvb + l15 * TSX + i * 32 + mt * 16 + q4 * 4) = p;
        }
    }

    // ---- v = a @ xv -> val_s[:, h*16 + 0..15] (wave-private columns) ----
#pragma unroll
    for (int i = 0; i < 2; ++i)
#pragma unroll
      for (int lt = 0; lt < 2; ++lt) {
        v8s af = *(const v8s*)(tb + ((i * 2 + lt) * 16 + l15) * TS + q4 * 8);
        v8s bv = *(const v8s*)(xvb + l15 * TSX + i * 32 + q4 * 8);
        v4f vv = MFMA(af, bv, Z4);
#pragma unroll
        for (int r = 0; r < 4; ++r)
          val_s[i * (32 * VS) + (lt * 16 + q4 * 4 + r) * VS + h * 16 + l15] =
              f2b(vv[r]);
      }
  }
  __syncthreads();

  // ---- keyw = tanh(val@WkT + bk); wl = SCALE * qw . keyw ----
  // 4 waves: (itm, lt); each wave covers all 16 d-tiles.
  {
    int itm = w >> 1, lt = w & 1;
    const bf16u* vrow = &val_s[itm * (32 * VS) + (lt * 16 + l15) * VS + q4 * 8];
    v8s af2[8];
#pragma unroll
    for (int ks = 0; ks < 8; ++ks) af2[ks] = *(const v8s*)(vrow + ks * 32);
    float wlp[4] = {0.f, 0.f, 0.f, 0.f};
#pragma unroll
    for (int k = 0; k < 16; ++k) {
      int d = k * 16 + l15;
      float bkf = (d < NQD) ? bk[d] : 0.f;
      float qwf = (d < NQD) ? qw[d] : 0.f;
      v4f acc = Z4;
      const bf16u* bp2 = wkT + d * NR + q4 * 8;
#pragma unroll
      for (int ks = 0; ks < 8; ++ks) {
        v8s b = *(const v8s*)(bp2 + ks * 32);
        acc = MFMA(af2[ks], b, acc);
      }
#pragma unroll
      for (int r = 0; r < 4; ++r)
        wlp[r] += tanhf(acc[r] + bkf) * qwf;
    }
#pragma unroll
    for (int r = 0; r < 4; ++r) {
      float tv = wlp[r] * SCALE;
      tv += __shfl_xor(tv, 1);
      tv += __shfl_xor(tv, 2);
      tv += __shfl_xor(tv, 4);
      tv += __shfl_xor(tv, 8);
      if (l15 == 0) wl_s[itm * 32 + lt * 16 + q4 * 4 + r] = tv;
    }
  }
  __syncthreads();

  // ---- ww = softmax(wl) per item (lanes 0-31 item0, 32-63 item1) ----
  if (tid < 64) {
    float v = wl_s[tid];
    float mx = v;
#pragma unroll
    for (int off = 1; off < 32; off <<= 1) mx = fmaxf(mx, __shfl_xor(mx, off, 32));
    float e = __expf(v - mx);
    float sum = e;
#pragma unroll
    for (int off = 1; off < 32; off <<= 1) sum += __shfl_xor(sum, off, 32);
    ww_s[tid] = e / sum;
  }
  __syncthreads();

  // ---- rep[r] = sum_l ww[l]*val[l][r] ----
#pragma unroll
  for (int itm = 0; itm < 2; ++itm) {
    const bf16u* vb2 = &val_s[itm * (32 * VS) + tid];
    float sv = 0.f;
#pragma unroll 8
    for (int l = 0; l < 32; ++l) sv += ww_s[itm * 32 + l] * b2f(vb2[l * VS]);
    rep[(size_t)(g0 + itm) * NR + tid] = sv;
  }
  // ---- hval writeback (clicked items only), coalesced uint4 ----
  if (g0 >= NB * NCDD) {
    for (int c = tid; c < 2048; c += 256) {
      int itm = c >> 10, l = (c >> 5) & 31, j = c & 31;
      *(uint4*)(hval + (size_t)(g0 + itm) * (NL * NR) + l * NR + j * 8) =
          *(const uint4*)(&val_s[itm * (32 * VS) + l * VS + j * 8]);
    }
  }
}

// ---------------------------------------------------------------------------
// select: one block per (b,c): score[h] = cdd_rep.his_rep + gumbel (h<40),
// argmax, gather. grid = 160.
// ---------------------------------------------------------------------------
__global__ __launch_bounds__(256) void select_kernel(
    const float* __restrict__ rep, const float* __restrict__ gumbel,
    const bf16u* __restrict__ hval, float* __restrict__ out) {
  __shared__ float score[NMASK];
  __shared__ int hstar;
  const float* cdd_rep = rep;
  const float* his_rep = rep + (size_t)(NB * NCDD) * NR;
  const bf16u* his_val = hval + (size_t)(NB * NCDD) * (NL * NR);
  int b = blockIdx.x / NCDD, c = blockIdx.x % NCDD;
  int tid = threadIdx.x, lane = tid & 63, wv = tid >> 6;
  const float* cr = cdd_rep + (size_t)(b * NCDD + c) * NR;
  for (int h = wv; h < NMASK; h += 4) {
    const float* hr = his_rep + (size_t)(b * NHIS + h) * NR;
    float s = 0.f;
#pragma unroll
    for (int j = 0; j < 4; ++j) s += cr[lane * 4 + j] * hr[lane * 4 + j];
#pragma unroll
    for (int off = 1; off < 64; off <<= 1) s += __shfl_xor(s, off);
    if (lane == 0)
      score[h] = s + gumbel[(b * NCDD + c) * NHIS + h];
  }
  __syncthreads();
  if (tid == 0) {
    float best = -1e30f;
    int bi = 0;
    for (int h = 0; h < NMASK; ++h) {
      float v = score[h];
      if (v > best) { best = v; bi = h; }  // strict > keeps first max
    }
    hstar = bi;
  }
  __syncthreads();
  const bf16u* src = his_val + (size_t)(b * NHIS + hstar) * (NL * NR);
  float* dst = out + (size_t)(b * NCDD + c) * (NL * NR);
  for (int k = tid; k < 2048; k += 256) {
    const bf16u* sp = src + k * 4;
    float4 o;
    o.x = b2f(sp[0]); o.y = b2f(sp[1]); o.z = b2f(sp[2]); o.w = b2f(sp[3]);
    *(float4*)(dst + k * 4) = o;
  }
}

extern "C" void kernel_launch(void* const* d_in, const int* in_sizes, int n_in,
                              void* d_out, int out_size, void* d_ws, size_t ws_size,
                              hipStream_t stream) {
  (void)in_sizes; (void)n_in; (void)out_size; (void)ws_size;
  const int* cand = (const int*)d_in[0];
  const int* clk = (const int*)d_in[1];
  // d_in[2] his_mask (static: h>=40), d_in[3]/d_in[4] pads: unused
  const float* gum = (const float*)d_in[5];
  const float* emb = (const float*)d_in[6];
  const float* wq = (const float*)d_in[7];
  const float* wvp = (const float*)d_in[8];
  const float* wk = (const float*)d_in[9];
  const float* bk = (const float*)d_in[10];
  const float* qw = (const float*)d_in[11];

  char* ws = (char*)d_ws;
  bf16u* wqB = (bf16u*)(ws + WQB_OFF);
  bf16u* wvT = (bf16u*)(ws + WVT_OFF);
  bf16u* wkT = (bf16u*)(ws + WKT_OFF);
  float* rep = (float*)(ws + REP_OFF);
  bf16u* hval = (bf16u*)(ws + HVAL_OFF);

  const int totalT = 16 * 320 * 320 + 16 * 16 * 320 + 256 * 256;  // 1,785,856
  hipLaunchKernelGGL(prep_kernel, dim3((totalT + 255) / 256), dim3(256), 0, stream,
                     wq, wvp, wk, wqB, wvT, wkT);
  hipLaunchKernelGGL(encode_kernel, dim3(NITEM / 2), dim3(256), 0, stream,
                     cand, clk, emb, wqB, wvT, wkT, bk, qw, rep, hval);
  hipLaunchKernelGGL(select_kernel, dim3(NB * NCDD), dim3(256), 0, stream,
                     rep, gum, hval, (float*)d_out);
}